// Round 1
// baseline (105.911 us; speedup 1.0000x reference)
//
#include <hip/hip_runtime.h>

#define NV 1084
#define NJR 21

// ws layout (floats):
//  [0, B*192)            A_rel  [B][16][12]   (rows 0..2 of each 4x4)
//  [B*192, +1344)        M      [21][16][4]   (M[j][k][0..2]=sum Jreg*w*vt, [3]=sum Jreg*w)
//  next 48               Jt     [16][3]
//  next B*45             euler_pose [B][45]

__device__ inline void rodrigues9(float x, float y, float z, float R[9]) {
    float n2 = x * x + y * y + z * z + 1e-8f;
    float angle = sqrtf(n2);
    float inv = 1.0f / angle;
    float ax = x * inv, ay = y * inv, az = z * inv;
    float c = cosf(angle), s = sinf(angle);
    float C = 1.0f - c;
    R[0] = 1.0f - C * (ay * ay + az * az);
    R[1] = -s * az + C * ax * ay;
    R[2] = s * ay + C * ax * az;
    R[3] = s * az + C * ax * ay;
    R[4] = 1.0f - C * (ax * ax + az * az);
    R[5] = -s * ax + C * ay * az;
    R[6] = -s * ay + C * ax * az;
    R[7] = s * ax + C * ay * az;
    R[8] = 1.0f - C * (ax * ax + ay * ay);
}

// Batch-independent reductions over vertices: M[21][16][4] and Jt[16][3].
__global__ __launch_bounds__(384) void precompute_kernel(
    const float* __restrict__ vt, const float* __restrict__ jreg,
    const float* __restrict__ wts, float* __restrict__ Mbuf, float* __restrict__ jt) {
    int t = threadIdx.x;
    int v0 = blockIdx.x * 17;
    int v1 = min(v0 + 17, NV);
    if (t < 336) {
        int j = t >> 4, k = t & 15;
        float m0 = 0.f, m1 = 0.f, m2 = 0.f, s = 0.f;
        for (int v = v0; v < v1; ++v) {
            float jw = jreg[v * 21 + j] * wts[v * 16 + k];
            m0 += jw * vt[v * 3 + 0];
            m1 += jw * vt[v * 3 + 1];
            m2 += jw * vt[v * 3 + 2];
            s += jw;
        }
        float* mp = Mbuf + (t << 2);
        atomicAdd(mp + 0, m0);
        atomicAdd(mp + 1, m1);
        atomicAdd(mp + 2, m2);
        atomicAdd(mp + 3, s);
    } else if (t < 336 + 48) {
        int o = t - 336;
        int j = o / 3, c = o % 3;  // j < 16
        float acc = 0.f;
        for (int v = v0; v < v1; ++v) acc += vt[v * 3 + c] * jreg[v * 21 + j];
        atomicAdd(&jt[o], acc);
    }
}

// euler_pose[b,col] = hm[col] + sum_k theta[b,k] * hc[k,col]
__global__ __launch_bounds__(256) void euler_kernel(
    const float* __restrict__ theta, const float* __restrict__ hc,
    const float* __restrict__ hm, float* __restrict__ out, int total) {
    int i = blockIdx.x * 256 + threadIdx.x;
    if (i >= total) return;
    int b = i / 45, col = i % 45;
    const float* th = theta + b * 45;
    float acc = hm[col];
#pragma unroll
    for (int k = 0; k < 45; ++k) acc += th[k] * hc[k * 45 + col];
    out[i] = acc;
}

// Forward kinematics: one thread per batch. Writes A_rel[b][16][12].
__global__ __launch_bounds__(64) void fk_kernel(
    const float* __restrict__ wrist, const float* __restrict__ euler,
    const float* __restrict__ jt, float* __restrict__ wsA) {
    __shared__ float sj[48];
    int t = threadIdx.x;
    if (t < 48) sj[t] = jt[t];
    __syncthreads();
    int b = blockIdx.x * 64 + t;
    float R[9];
    rodrigues9(wrist[b * 3 + 0], wrist[b * 3 + 1], wrist[b * 3 + 2], R);
    float J0x = sj[0], J0y = sj[1], J0z = sj[2];
    float A0[12];
    A0[0] = R[0]; A0[1] = R[1]; A0[2] = R[2]; A0[3] = J0x;
    A0[4] = R[3]; A0[5] = R[4]; A0[6] = R[5]; A0[7] = J0y;
    A0[8] = R[6]; A0[9] = R[7]; A0[10] = R[8]; A0[11] = J0z;
    float* out = wsA + (size_t)b * 192;
#pragma unroll
    for (int r = 0; r < 3; ++r) {
        out[r * 4 + 0] = A0[r * 4 + 0];
        out[r * 4 + 1] = A0[r * 4 + 1];
        out[r * 4 + 2] = A0[r * 4 + 2];
        out[r * 4 + 3] = A0[r * 4 + 3] -
            (A0[r * 4 + 0] * J0x + A0[r * 4 + 1] * J0y + A0[r * 4 + 2] * J0z);
    }
    const float* eb = euler + (size_t)b * 45;
#pragma unroll
    for (int chain = 0; chain < 5; ++chain) {
        float Ap[12];
#pragma unroll
        for (int q = 0; q < 12; ++q) Ap[q] = A0[q];
        int p = 0;
#pragma unroll
        for (int step = 0; step < 3; ++step) {
            int i = chain * 3 + step + 1;
            int cb = 3 * (i - 1);
            rodrigues9(eb[cb + 0], eb[cb + 1], eb[cb + 2], R);
            float tx = sj[i * 3 + 0] - sj[p * 3 + 0];
            float ty = sj[i * 3 + 1] - sj[p * 3 + 1];
            float tz = sj[i * 3 + 2] - sj[p * 3 + 2];
            float An[12];
#pragma unroll
            for (int r = 0; r < 3; ++r) {
                An[r * 4 + 0] = Ap[r * 4 + 0] * R[0] + Ap[r * 4 + 1] * R[3] + Ap[r * 4 + 2] * R[6];
                An[r * 4 + 1] = Ap[r * 4 + 0] * R[1] + Ap[r * 4 + 1] * R[4] + Ap[r * 4 + 2] * R[7];
                An[r * 4 + 2] = Ap[r * 4 + 0] * R[2] + Ap[r * 4 + 1] * R[5] + Ap[r * 4 + 2] * R[8];
                An[r * 4 + 3] = Ap[r * 4 + 3] + Ap[r * 4 + 0] * tx + Ap[r * 4 + 1] * ty + Ap[r * 4 + 2] * tz;
            }
            float jx = sj[i * 3 + 0], jy = sj[i * 3 + 1], jz = sj[i * 3 + 2];
            float* oi = out + i * 12;
#pragma unroll
            for (int r = 0; r < 3; ++r) {
                oi[r * 4 + 0] = An[r * 4 + 0];
                oi[r * 4 + 1] = An[r * 4 + 1];
                oi[r * 4 + 2] = An[r * 4 + 2];
                oi[r * 4 + 3] = An[r * 4 + 3] -
                    (An[r * 4 + 0] * jx + An[r * 4 + 1] * jy + An[r * 4 + 2] * jz);
            }
#pragma unroll
            for (int q = 0; q < 12; ++q) Ap[q] = An[q];
            p = i;
        }
    }
}

// joints[b,j,c] = sum_k sum_d M[j][k][d] * A[b][k][c*4+d]
__global__ __launch_bounds__(256) void joints_kernel(
    const float* __restrict__ wsA, const float* __restrict__ Mbuf,
    float* __restrict__ jout, int total) {
    __shared__ float sM[1344];
    int t = threadIdx.x;
    for (int q = t; q < 1344; q += 256) sM[q] = Mbuf[q];
    __syncthreads();
    int i = blockIdx.x * 256 + t;
    if (i >= total) return;
    int b = i / 63, o = i % 63;
    int j = o / 3, c = o % 3;
    const float* A = wsA + (size_t)b * 192 + c * 4;
    const float* Mj = &sM[j * 64];
    float acc = 0.f;
#pragma unroll
    for (int k = 0; k < 16; ++k) {
        float4 a = *(const float4*)&A[k * 12];
        float4 m = *(const float4*)&Mj[k * 4];
        acc += a.x * m.x + a.y * m.y + a.z * m.z + a.w * m.w;
    }
    jout[i] = acc;
}

// verts: block = (batch-group of 4) x (chunk of 256 vertices)
__global__ __launch_bounds__(256) void verts_kernel(
    const float* __restrict__ wsA, const float* __restrict__ wts,
    const float* __restrict__ vt, float* __restrict__ verts) {
    __shared__ float sA[4 * 192];
    int bi = blockIdx.x;
    int bg = bi / 5, chunk = bi % 5;
    int t = threadIdx.x;
    const float* src = wsA + (size_t)bg * 768;
    for (int q = t; q < 768; q += 256) sA[q] = src[q];
    __syncthreads();
    int v = chunk * 256 + t;
    if (v >= NV) return;
    float4 w0 = *(const float4*)&wts[v * 16 + 0];
    float4 w1 = *(const float4*)&wts[v * 16 + 4];
    float4 w2 = *(const float4*)&wts[v * 16 + 8];
    float4 w3 = *(const float4*)&wts[v * 16 + 12];
    float wv[16] = {w0.x, w0.y, w0.z, w0.w, w1.x, w1.y, w1.z, w1.w,
                    w2.x, w2.y, w2.z, w2.w, w3.x, w3.y, w3.z, w3.w};
    float vx = vt[v * 3 + 0], vy = vt[v * 3 + 1], vz = vt[v * 3 + 2];
#pragma unroll
    for (int bb = 0; bb < 4; ++bb) {
        const float* A = &sA[bb * 192];
        float T[12];
#pragma unroll
        for (int q = 0; q < 12; ++q) T[q] = wv[0] * A[q];
#pragma unroll
        for (int k = 1; k < 16; ++k) {
            float wk = wv[k];
#pragma unroll
            for (int q = 0; q < 12; ++q) T[q] += wk * A[k * 12 + q];
        }
        float ox = T[0] * vx + T[1] * vy + T[2] * vz + T[3];
        float oy = T[4] * vx + T[5] * vy + T[6] * vz + T[7];
        float oz = T[8] * vx + T[9] * vy + T[10] * vz + T[11];
        int b = bg * 4 + bb;
        float* o = verts + (size_t)b * (NV * 3) + v * 3;
        o[0] = ox;
        o[1] = oy;
        o[2] = oz;
    }
}

extern "C" void kernel_launch(void* const* d_in, const int* in_sizes, int n_in,
                              void* d_out, int out_size, void* d_ws, size_t ws_size,
                              hipStream_t stream) {
    const float* theta = (const float*)d_in[1];
    const float* wrist = (const float*)d_in[2];
    const float* vtpl  = (const float*)d_in[3];
    const float* jreg  = (const float*)d_in[4];
    const float* hc    = (const float*)d_in[5];
    const float* hm    = (const float*)d_in[6];
    const float* wts   = (const float*)d_in[7];
    int B = in_sizes[1] / 45;  // 4096

    float* ws    = (float*)d_ws;
    float* wsA   = ws;                       // B*192
    float* Mbuf  = ws + (size_t)B * 192;     // 1344
    float* jt    = Mbuf + 1344;              // 48
    float* euler = jt + 48;                  // B*45
    float* verts = (float*)d_out;
    float* jout  = verts + (size_t)B * NV * 3;

    hipMemsetAsync(Mbuf, 0, (1344 + 48) * sizeof(float), stream);
    precompute_kernel<<<64, 384, 0, stream>>>(vtpl, jreg, wts, Mbuf, jt);
    euler_kernel<<<(B * 45 + 255) / 256, 256, 0, stream>>>(theta, hc, hm, euler, B * 45);
    fk_kernel<<<B / 64, 64, 0, stream>>>(wrist, euler, jt, wsA);
    joints_kernel<<<(B * 63 + 255) / 256, 256, 0, stream>>>(wsA, Mbuf, jout, B * 63);
    verts_kernel<<<(B / 4) * 5, 256, 0, stream>>>(wsA, wts, vtpl, verts);
}